// Round 10
// baseline (163.959 us; speedup 1.0000x reference)
//
#include <hip/hip_runtime.h>
#include <math.h>

#define B_   4
#define N_   4096
#define C_   256
#define D_   32
#define QT   32
#define KTB  128
#define NT2  32
#define L2E  1.4426950408889634f

typedef __attribute__((ext_vector_type(8)))  short  short8;
typedef __attribute__((ext_vector_type(4)))  float  f32x4;
typedef __attribute__((ext_vector_type(16))) float  f32x16;
typedef __attribute__((ext_vector_type(4)))  unsigned u32x4;

__device__ __forceinline__ unsigned short f2bf(float f) {
    unsigned int u = __builtin_bit_cast(unsigned int, f);
    u += 0x7fffu + ((u >> 16) & 1u);
    return (unsigned short)(u >> 16);
}
__device__ __forceinline__ unsigned pack2(float lo, float hi) {
    return (unsigned)f2bf(lo) | ((unsigned)f2bf(hi) << 16);
}
// cheap round-to-nearest bf16 pack (no tie-to-even): fine for P
__device__ __forceinline__ unsigned pack2rn(float lo, float hi) {
    unsigned ul = __builtin_bit_cast(unsigned, lo) + 0x8000u;
    unsigned uh = __builtin_bit_cast(unsigned, hi) + 0x8000u;
    return (ul >> 16) | (uh & 0xffff0000u);
}

// ---------------- weight cast+transpose: WT[320][256] bf16 ----------------
__global__ __launch_bounds__(64) void wcast(const float* __restrict__ Wf,
        const float* __restrict__ Wg, const float* __restrict__ Wh,
        unsigned short* __restrict__ WT) {
    const int e = blockIdx.x;
    const int t = threadIdx.x;
    const float* src; int stride, col;
    if (e < 256)      { src = Wh; stride = 256; col = e; }
    else if (e < 288) { src = Wf; stride = 32;  col = e - 256; }
    else              { src = Wg; stride = 32;  col = e - 288; }
    const int c0 = t * 4;
    __align__(8) unsigned short tmp[4];
    #pragma unroll
    for (int i = 0; i < 4; ++i)
        tmp[i] = f2bf(src[(size_t)(c0 + i) * stride + col]);
    *(uint2*)(WT + (size_t)e * 256 + c0) = *(const uint2*)tmp;
}

// ---------------- fused projection GEMM (MFMA bf16) -----------------------
__global__ __launch_bounds__(256, 2) void proj(const float* __restrict__ x,
        const unsigned short* __restrict__ WT,
        unsigned short* __restrict__ f, unsigned short* __restrict__ g,
        unsigned short* __restrict__ hT) {
    __shared__ unsigned short xb[32 * 256];
    const int t = threadIdx.x;
    const int l = t & 63, w = t >> 6;
    const long n0 = (long)blockIdx.x * 32;
    const int b = (int)(n0 >> 12), nloc = (int)(n0 & 4095);

    {
        const int r = t >> 3, ch = (t & 7) * 32;
        const float* xp = x + (n0 + r) * C_ + ch;
        #pragma unroll
        for (int m4 = 0; m4 < 8; ++m4) {
            float4 v = *(const float4*)(xp + m4 * 4);
            unsigned u0 = pack2(v.x, v.y), u1 = pack2(v.z, v.w);
            const int byte = (r * 512 + (ch + m4 * 4) * 2) ^ ((r & 7) << 4);
            *(uint2*)((char*)xb + byte) = make_uint2(u0, u1);
        }
    }
    __syncthreads();

    const int l15 = l & 15, l31 = l & 31;
    const int l4 = (l >> 4) & 3, hi = (l >> 5) & 1;

    f32x16 acc0, acc1;
    #pragma unroll
    for (int i = 0; i < 16; ++i) { acc0[i] = 0.f; acc1[i] = 0.f; }
    const int e0 = w * 64 + l31;
    #pragma unroll
    for (int ks = 0; ks < 16; ++ks) {
        short8 A = *(const short8*)((const char*)xb +
                    ((l31 * 512 + ks * 32 + hi * 16) ^ ((l31 & 7) << 4)));
        short8 B0 = *(const short8*)(WT + (size_t)e0 * 256 + ks * 16 + hi * 8);
        short8 B1 = *(const short8*)(WT + (size_t)(e0 + 32) * 256 + ks * 16 + hi * 8);
        acc0 = __builtin_amdgcn_mfma_f32_32x32x16_bf16(A, B0, acc0, 0, 0, 0);
        acc1 = __builtin_amdgcn_mfma_f32_32x32x16_bf16(A, B1, acc1, 0, 0, 0);
    }
    f32x4 fgacc[2];
    #pragma unroll
    for (int rf = 0; rf < 2; ++rf)
        #pragma unroll
        for (int i = 0; i < 4; ++i) fgacc[rf][i] = 0.f;
    const int fcol = w * 16 + l15;
    #pragma unroll
    for (int ks2 = 0; ks2 < 8; ++ks2) {
        short8 Bf = *(const short8*)(WT + (size_t)(256 + fcol) * 256 + ks2 * 32 + l4 * 8);
        #pragma unroll
        for (int rf = 0; rf < 2; ++rf) {
            const int row = rf * 16 + l15;
            short8 A = *(const short8*)((const char*)xb +
                        ((row * 512 + ks2 * 64 + l4 * 16) ^ ((row & 7) << 4)));
            fgacc[rf] = __builtin_amdgcn_mfma_f32_16x16x32_bf16(A, Bf, fgacc[rf], 0, 0, 0);
        }
    }

    #pragma unroll
    for (int ef = 0; ef < 2; ++ef) {
        const f32x16& a = ef ? acc1 : acc0;
        const int e = e0 + ef * 32;
        unsigned short* dp = hT + ((size_t)b * C_ + e) * N_ + nloc + 4 * hi;
        #pragma unroll
        for (int qd = 0; qd < 4; ++qd) {
            unsigned u0 = pack2(a[4*qd+0], a[4*qd+1]);
            unsigned u1 = pack2(a[4*qd+2], a[4*qd+3]);
            *(uint2*)(dp + 8 * qd) = make_uint2(u0, u1);
        }
    }
    {
        unsigned short* outp = (fcol < 32) ? (f + fcol) : (g + fcol - 32);
        #pragma unroll
        for (int rf = 0; rf < 2; ++rf)
            #pragma unroll
            for (int r = 0; r < 4; ++r) {
                const int row = rf * 16 + l4 * 4 + r;
                outp[(size_t)(n0 + row) * D_] = f2bf(fgacc[rf][r]);
            }
    }
}

// ---------------- flash attention: barrier-free, in-register P -------------
// grid 512 blocks (q-tile 32 x batch, XCD-swizzled), 512 thr = 8 waves.
// Wave w = (eh = w>>2, kq = w&3): e-half eh*128, k-quarter kq*32 per 128-tile.
// QK: S^T[k32][q32] = mfma32(f, g) x2 (d-blocks). P stays in registers:
// shfl_xor(32)+select reshapes S^T C-frags into PV A-frags. PV accumulates
// O_partial[q32][e128] in 4 f32x16. NO barriers in the k-loop. Final
// k-quarter reduction via padded LDS + fused epilogue.
__global__ __launch_bounds__(512, 2) void attn(
        const unsigned short* __restrict__ g,
        const unsigned short* __restrict__ f,
        const unsigned short* __restrict__ hT,
        const float* __restrict__ x,
        const float* __restrict__ gammap,
        float* __restrict__ out) {

    __shared__ __align__(16) float red[2][4][32][132];  // 135168 B, rows 528B (33x16B: conflict-free)
    __shared__ float Lp[4][32];

    const int bid = (int)blockIdx.x;
    const int s = (bid & 7) * 64 + (bid >> 3);   // bijective XCD swizzle
    const int b  = s >> 7;
    const int q0 = (s & 127) * QT;

    const int t = threadIdx.x, l = t & 63, w = t >> 6;
    const int l31 = l & 31, hi = l >> 5;
    const int eh = w >> 2, kq = w & 3;
    const long nb = (long)b * N_;

    // const g B-frags: B[d][col=q=l31], d = dblk*16 + hi*8 + j
    const unsigned short* gp = g + (size_t)(nb + q0 + l31) * D_ + hi * 8;
    const short8 gB0 = *(const short8*)(gp);
    const short8 gB1 = *(const short8*)(gp + 16);

    // f A-frags: A[row=k=l31 (within wave k32)][d same split]; prefetched
    const unsigned short* fp = f + (size_t)(nb + kq * 32 + l31) * D_ + hi * 8;
    short8 fA0 = *(const short8*)(fp);
    short8 fA1 = *(const short8*)(fp + 16);

    // h B-frag rows: hT[e][n], e = eh*128 + eb*32 + l31, k at +hi*8
    const unsigned short* hbase = hT + ((size_t)b * C_ + eh * 128 + l31) * N_ + hi * 8;
    const unsigned short* hr0 = hbase;
    const unsigned short* hr1 = hbase + (size_t)32 * N_;
    const unsigned short* hr2 = hbase + (size_t)64 * N_;
    const unsigned short* hr3 = hbase + (size_t)96 * N_;

    float la = 0.f;
    f32x16 acc0, acc1, acc2, acc3, zz16;
    #pragma unroll
    for (int i = 0; i < 16; ++i) {
        zz16[i] = 0.f; acc0[i] = 0.f; acc1[i] = 0.f; acc2[i] = 0.f; acc3[i] = 0.f;
    }

    #pragma unroll 1
    for (int kt = 0; kt < NT2; ++kt) {
        const int kg = kt * KTB + kq * 32;
        // h loads for THIS tile (used ~700cyc later in PV)
        short8 h00 = *(const short8*)(hr0 + kg);
        short8 h01 = *(const short8*)(hr0 + kg + 16);
        short8 h10 = *(const short8*)(hr1 + kg);
        short8 h11 = *(const short8*)(hr1 + kg + 16);
        short8 h20 = *(const short8*)(hr2 + kg);
        short8 h21 = *(const short8*)(hr2 + kg + 16);
        short8 h30 = *(const short8*)(hr3 + kg);
        short8 h31 = *(const short8*)(hr3 + kg + 16);
        // f prefetch for next tile (reads ≤1 tile past fb into ws: harmless)
        const unsigned short* fn = fp + (size_t)(kt + 1) * (KTB * D_);
        short8 fP0 = *(const short8*)(fn);
        short8 fP1 = *(const short8*)(fn + 16);

        // QK: S^T[k-off][q], k-off(lane,reg) = (reg&3)+8*(reg>>2)+4*hi
        f32x16 S = __builtin_amdgcn_mfma_f32_32x32x16_bf16(fA0, gB0, zz16, 0, 0, 0);
        S = __builtin_amdgcn_mfma_f32_32x32x16_bf16(fA1, gB1, S, 0, 0, 0);

        // expand + pack pairs (consecutive k): pk[i] = (p[2i], p[2i+1])
        float p[16];
        unsigned pk[8];
        #pragma unroll
        for (int r = 0; r < 16; ++r)
            p[r] = exp2f(fminf(S[r], 60.f) * L2E);
        #pragma unroll
        for (int i = 0; i < 8; ++i) {
            la += p[2*i] + p[2*i+1];
            pk[i] = pack2rn(p[2*i], p[2*i+1]);
        }

        // reshape to PV A-frags: A[row=q=l31][k = kb*16 + hi*8 + j]
        // j<4 from hi'=0 lane (same q), j>=4 from hi'=1 lane; reg-group by
        // target hi. shfl_xor(32) provides the opposite-half values.
        short8 pA0, pA1;
        {
            const unsigned s0 = (unsigned)__shfl_xor((int)pk[0], 32, 64);
            const unsigned s1 = (unsigned)__shfl_xor((int)pk[1], 32, 64);
            const unsigned s2 = (unsigned)__shfl_xor((int)pk[2], 32, 64);
            const unsigned s3 = (unsigned)__shfl_xor((int)pk[3], 32, 64);
            u32x4 v;
            v[0] = hi ? s2 : pk[0];
            v[1] = hi ? s3 : pk[1];
            v[2] = hi ? pk[2] : s0;
            v[3] = hi ? pk[3] : s1;
            pA0 = __builtin_bit_cast(short8, v);
        }
        {
            const unsigned s4 = (unsigned)__shfl_xor((int)pk[4], 32, 64);
            const unsigned s5 = (unsigned)__shfl_xor((int)pk[5], 32, 64);
            const unsigned s6 = (unsigned)__shfl_xor((int)pk[6], 32, 64);
            const unsigned s7 = (unsigned)__shfl_xor((int)pk[7], 32, 64);
            u32x4 v;
            v[0] = hi ? s6 : pk[4];
            v[1] = hi ? s7 : pk[5];
            v[2] = hi ? pk[6] : s4;
            v[3] = hi ? pk[7] : s5;
            pA1 = __builtin_bit_cast(short8, v);
        }

        // PV: O[q][e] += P[q][k] h[k][e]
        acc0 = __builtin_amdgcn_mfma_f32_32x32x16_bf16(pA0, h00, acc0, 0, 0, 0);
        acc0 = __builtin_amdgcn_mfma_f32_32x32x16_bf16(pA1, h01, acc0, 0, 0, 0);
        acc1 = __builtin_amdgcn_mfma_f32_32x32x16_bf16(pA0, h10, acc1, 0, 0, 0);
        acc1 = __builtin_amdgcn_mfma_f32_32x32x16_bf16(pA1, h11, acc1, 0, 0, 0);
        acc2 = __builtin_amdgcn_mfma_f32_32x32x16_bf16(pA0, h20, acc2, 0, 0, 0);
        acc2 = __builtin_amdgcn_mfma_f32_32x32x16_bf16(pA1, h21, acc2, 0, 0, 0);
        acc3 = __builtin_amdgcn_mfma_f32_32x32x16_bf16(pA0, h30, acc3, 0, 0, 0);
        acc3 = __builtin_amdgcn_mfma_f32_32x32x16_bf16(pA1, h31, acc3, 0, 0, 0);

        fA0 = fP0; fA1 = fP1;
    }

    // ---- partial row-sum: combine lane halves (hi covers disjoint k-offs)
    la += __shfl_xor(la, 32, 64);
    if (eh == 0 && l < 32) Lp[kq][l] = la;   // eh=1 waves duplicate QK

    // ---- write O_partial to LDS: red[eh][kq][q][e']
    {
        float* rw = &red[eh][kq][0][0];
        #pragma unroll
        for (int reg = 0; reg < 16; ++reg) {
            const int q = (reg & 3) + 8 * (reg >> 2) + 4 * hi;
            rw[q * 132 +   0 + l31] = acc0[reg];
            rw[q * 132 +  32 + l31] = acc1[reg];
            rw[q * 132 +  64 + l31] = acc2[reg];
            rw[q * 132 +  96 + l31] = acc3[reg];
        }
    }
    __syncthreads();

    // ---- reduce over kq + epilogue. Wave w owns e-cols [w*32, w*32+32).
    {
        const int ehr = w >> 2, ebr = w & 3;
        const float lsum = Lp[0][l31] + Lp[1][l31] + Lp[2][l31] + Lp[3][l31];
        const float linv = 1.f / fmaxf(lsum, 1e-30f);
        const float gm = gammap[0];
        const size_t obase = (size_t)(nb + q0 + l31) * C_ + w * 32 + hi * 16;
        #pragma unroll
        for (int c4 = 0; c4 < 4; ++c4) {
            const int e4 = ebr * 32 + hi * 16 + c4 * 4;
            float4 s0 = *(float4*)&red[ehr][0][l31][e4];
            float4 s1 = *(float4*)&red[ehr][1][l31][e4];
            float4 s2 = *(float4*)&red[ehr][2][l31][e4];
            float4 s3 = *(float4*)&red[ehr][3][l31][e4];
            float4 xv = *(const float4*)(x + obase + c4 * 4);
            float4 r;
            r.x = fmaf(gm, (s0.x + s1.x + s2.x + s3.x) * linv, xv.x);
            r.y = fmaf(gm, (s0.y + s1.y + s2.y + s3.y) * linv, xv.y);
            r.z = fmaf(gm, (s0.z + s1.z + s2.z + s3.z) * linv, xv.z);
            r.w = fmaf(gm, (s0.w + s1.w + s2.w + s3.w) * linv, xv.w);
            *(float4*)(out + obase + c4 * 4) = r;
        }
    }
}

extern "C" void kernel_launch(void* const* d_in, const int* in_sizes, int n_in,
                              void* d_out, int out_size, void* d_ws, size_t ws_size,
                              hipStream_t stream) {
    const float* x     = (const float*)d_in[0];
    const float* Wf    = (const float*)d_in[1];
    const float* Wg    = (const float*)d_in[2];
    const float* Wh    = (const float*)d_in[3];
    const float* gamma = (const float*)d_in[4];
    float* out = (float*)d_out;

    unsigned short* WT  = (unsigned short*)d_ws;
    unsigned short* fb  = WT + 320 * 256;
    unsigned short* gb  = fb + (size_t)B_ * N_ * D_;
    unsigned short* hTb = gb + (size_t)B_ * N_ * D_;

    wcast<<<dim3(320), dim3(64), 0, stream>>>(Wf, Wg, Wh, WT);
    proj <<<dim3(B_ * N_ / 32), dim3(256), 0, stream>>>(x, WT, fb, gb, hTb);
    attn <<<dim3(512), dim3(512), 0, stream>>>(gb, fb, hTb, x, gamma, out);
}